// Round 2
// baseline (204.529 us; speedup 1.0000x reference)
//
#include <hip/hip_runtime.h>
#include <stdint.h>

// Problem dims (LSTMCell: B=4096, IN=1024, H=1024)
#define Bn 4096
#define INn 1024
#define Hn 1024
#define Kn 2048   // IN + H
#define Nn 4096   // 4*H

// GEMM tile (m97-proven structure)
#define BM 128
#define BK 64
// N-tile = 128 B-rows = 4 gates x 32 h-positions (fused layout)

typedef __attribute__((ext_vector_type(8))) short bf16x8;
typedef __attribute__((ext_vector_type(4))) float f32x4;
typedef __attribute__((ext_vector_type(4))) unsigned short us4;

// ---------- helpers ----------
__device__ __forceinline__ unsigned short f2bf(float f) {
  // round-to-nearest-even f32 -> bf16
  uint32_t u = __float_as_uint(f);
  u += 0x7fffu + ((u >> 16) & 1u);
  return (unsigned short)(u >> 16);
}

typedef __attribute__((address_space(3))) unsigned int as3_uint;
typedef const __attribute__((address_space(1))) unsigned int as1_uint;

__device__ __forceinline__ void gload16(const unsigned short* g, unsigned short* l) {
  // async global->LDS, 16B per lane (size must be a literal).
  // LDS dest must be wave-uniform-base + lane*16 (it is: see staging index calc).
  __builtin_amdgcn_global_load_lds((as1_uint*)g, (as3_uint*)l, 16, 0, 0);
}

__device__ __forceinline__ float sigm(float x) { return 1.f / (1.f + __expf(-x)); }
__device__ __forceinline__ float tanh_fast(float x) { return 2.f / (1.f + __expf(-2.f * x)) - 1.f; }

// ---------- kernel 1: f32 -> bf16 pack with row remap ----------
// src row-major [rows][2^log2cols]; dst row-major [rows][dst_stride] at col offset.
__global__ void pack_bf16(const float* __restrict__ src, unsigned short* __restrict__ dst,
                          int log2cols, int dst_stride, int dst_col_off, long nquads) {
  long stride = (long)gridDim.x * blockDim.x;
  for (long q = (long)blockIdx.x * blockDim.x + threadIdx.x; q < nquads; q += stride) {
    long e = q << 2;
    int row = (int)(e >> log2cols);
    int col = (int)(e & ((1L << log2cols) - 1));
    float4 v = *(const float4*)(src + e);
    us4 o;
    o.x = f2bf(v.x); o.y = f2bf(v.y); o.z = f2bf(v.z); o.w = f2bf(v.w);
    *(us4*)(dst + (long)row * dst_stride + dst_col_off + col) = o;
  }
}

// ---------- kernel 2: fused GEMM + LSTM epilogue ----------
// A: [B][K] bf16 (x | h_prev).  Wbf: [4H][K] bf16, row g*1024+h = weight row of gate g.
// Block: 128 batch rows x 32 h-positions (x 4 gates).  4 waves (2x2):
//   wave (wr,wc): batch sub-rows wr*64.., h sub-range wc*16..
//   fragment n in [0,4) = gate n  -> each lane holds f,i,g,o for its outputs.
// Bs row rb in [0,128): gate = (rb>>4)&3, hoff = (rb>>6)*16 + (rb&15).
__global__ void lstm_gemm_fused(const unsigned short* __restrict__ A,
                                const unsigned short* __restrict__ Wbf,
                                const float* __restrict__ c_prev,
                                const float* __restrict__ bias,
                                float* __restrict__ out) {
  __shared__ unsigned short As[BM * BK];
  __shared__ unsigned short Bs[BM * BK];
  const int tid = threadIdx.x;
  const int lane = tid & 63;
  const int wid = tid >> 6;
  const int wr = wid >> 1;
  const int wc = wid & 1;
  const int brow = blockIdx.y * BM;     // batch tile
  const int h0 = blockIdx.x * 32;       // h tile (32 h-positions per block)

  const int srow = tid >> 3;            // 0..31
  const int skoff = (tid & 7) * 8;      // k elem offset (16B chunks)

  const int l15 = lane & 15;
  const int lk = (lane >> 4) * 8;

  f32x4 acc[4][4] = {};   // acc[m][n]: m = batch frag, n = GATE

  for (int kt = 0; kt < Kn / BK; ++kt) {
    const int k0 = kt * BK;
#pragma unroll
    for (int i = 0; i < 4; ++i) {
      // A staging: linear rows
      gload16(A + (long)(brow + i * 32 + srow) * Kn + k0 + skoff,
              &As[(i * 32 + srow) * BK + skoff]);
      // B staging: gate-interleaved row map (global addr per-lane is allowed;
      // LDS addr stays base + lane*16)
      const int rb = i * 32 + srow;
      const int grow = ((rb >> 4) & 3) * 1024 + h0 + ((rb >> 6) << 4) + (rb & 15);
      gload16(Wbf + (long)grow * Kn + k0 + skoff,
              &Bs[rb * BK + skoff]);
    }
    __syncthreads();
#pragma unroll
    for (int ks = 0; ks < 2; ++ks) {
      bf16x8 af[4], bfr[4];
#pragma unroll
      for (int m = 0; m < 4; ++m)
        af[m] = *(const bf16x8*)&As[(wr * 64 + m * 16 + l15) * BK + ks * 32 + lk];
#pragma unroll
      for (int n = 0; n < 4; ++n)
        bfr[n] = *(const bf16x8*)&Bs[(wc * 64 + n * 16 + l15) * BK + ks * 32 + lk];
#pragma unroll
      for (int m = 0; m < 4; ++m)
#pragma unroll
        for (int n = 0; n < 4; ++n)
          acc[m][n] = __builtin_amdgcn_mfma_f32_16x16x32_bf16(af[m], bfr[n], acc[m][n], 0, 0, 0);
    }
    __syncthreads();
  }

  // ---- fused LSTM epilogue, fully in-register ----
  // C/D layout (verified m89/m91): col = lane&15 (h within 16), row = (lane>>4)*4 + j
  const int hcol = h0 + wc * 16 + l15;            // global h in [0,1024)
  const float bf_ = bias[hcol];                    // f-gate bias
  const float bi_ = bias[1024 + hcol];
  const float bg_ = bias[2048 + hcol];
  const float bo_ = bias[3072 + hcol];
  const int rbase = brow + wr * 64 + ((lane >> 4) << 2);
  const long BH = (long)Bn * Hn;
#pragma unroll
  for (int m = 0; m < 4; ++m) {
#pragma unroll
    for (int j = 0; j < 4; ++j) {
      const long r = rbase + m * 16 + j;
      const float f = sigm(acc[m][0][j] + bf_);
      const float i_ = sigm(acc[m][1][j] + bi_);
      const float g = tanh_fast(acc[m][2][j] + bg_);
      const float o = sigm(acc[m][3][j] + bo_);
      const float cp = c_prev[r * Hn + hcol];
      const float ct = f * cp + i_ * g;
      const float ht = o * tanh_fast(ct);
      out[r * Hn + hcol] = ht;            // h_t
      out[BH + r * Hn + hcol] = ct;       // c_t
    }
  }
}

// ---------- launch ----------
extern "C" void kernel_launch(void* const* d_in, const int* in_sizes, int n_in,
                              void* d_out, int out_size, void* d_ws, size_t ws_size,
                              hipStream_t stream) {
  const float* x      = (const float*)d_in[0];
  const float* h_prev = (const float*)d_in[1];
  const float* c_prev = (const float*)d_in[2];
  const float* W      = (const float*)d_in[3];
  const float* bias   = (const float*)d_in[4];
  float* out = (float*)d_out;

  // workspace: A_bf16 (B x K, 16MB) | W_bf16 (4H x K, 16MB)
  unsigned short* Abf = (unsigned short*)d_ws;
  unsigned short* Wbf = Abf + (long)Bn * Kn;

  // pack x -> A[:, 0:1024], h_prev -> A[:, 1024:2048], W -> Wbf (straight cast)
  pack_bf16<<<2048, 256, 0, stream>>>(x, Abf, 10, Kn, 0, (long)Bn * INn / 4);
  pack_bf16<<<2048, 256, 0, stream>>>(h_prev, Abf, 10, Kn, INn, (long)Bn * Hn / 4);
  pack_bf16<<<2048, 256, 0, stream>>>(W, Wbf, 11, Kn, 0, (long)Nn * Kn / 4);

  // grid: x = h tiles (1024/32 = 32), y = batch tiles (4096/128 = 32)
  dim3 grid(Hn / 32, Bn / BM);
  lstm_gemm_fused<<<grid, 256, 0, stream>>>(Abf, Wbf, c_prev, bias, out);
}